// Round 3
// baseline (723.283 us; speedup 1.0000x reference)
//
#include <hip/hip_runtime.h>

// d_out layout: gcn_users [U][192] then gcn_items [I][192]
//   cols 0:64 = emb, 64:128 = gcn1, 128:192 = gcn2
//
// CSR (user-major + item-major) built in d_ws each launch with PACKED
// (col,val) int2 entries; gather-style SpMM, no output atomics.

// ---------------- CSR build ----------------

__global__ void count_kernel(const int* __restrict__ eu, const int* __restrict__ ei,
                             int* __restrict__ du, int* __restrict__ di, int E)
{
    int e = blockIdx.x * blockDim.x + threadIdx.x;
    if (e >= E) return;
    atomicAdd(&du[eu[e]], 1);
    atomicAdd(&di[ei[e]], 1);
}

// Exclusive scan within each 1024-block; block totals to bsums (if non-null).
__global__ void scan_block_kernel(const int* __restrict__ in, int n,
                                  int* __restrict__ out, int* __restrict__ bsums)
{
    __shared__ int tmp[1024];
    int idx = blockIdx.x * 1024 + threadIdx.x;
    int x = (idx < n) ? in[idx] : 0;
    tmp[threadIdx.x] = x;
    __syncthreads();
    #pragma unroll
    for (int off = 1; off < 1024; off <<= 1) {
        int t = (threadIdx.x >= off) ? tmp[threadIdx.x - off] : 0;
        __syncthreads();
        tmp[threadIdx.x] += t;
        __syncthreads();
    }
    if (idx < n) out[idx] = tmp[threadIdx.x] - x;
    if (threadIdx.x == 1023 && bsums) bsums[blockIdx.x] = tmp[1023];
}

// rp[idx] += block offset; also initialize write-pointer wp[idx] = rp[idx].
__global__ void scan_fixup_kernel(int* __restrict__ rp, int* __restrict__ wp,
                                  const int* __restrict__ bscan, int n, int total)
{
    int idx = blockIdx.x * blockDim.x + threadIdx.x;
    if (idx < n) {
        int v = rp[idx] + bscan[idx >> 10];
        rp[idx] = v;
        wp[idx] = v;
    } else if (idx == n) {
        rp[n] = total;
    }
}

__global__ void scatter_kernel(const int* __restrict__ eu, const int* __restrict__ ei,
                               const float* __restrict__ uiv, const float* __restrict__ iuv,
                               int* __restrict__ wpu, int* __restrict__ wpi,
                               unsigned long long* __restrict__ cv_u,
                               unsigned long long* __restrict__ cv_i, int E)
{
    int e = blockIdx.x * blockDim.x + threadIdx.x;
    if (e >= E) return;
    int u = eu[e], i = ei[e];
    unsigned long long pu = ((unsigned long long)__float_as_uint(uiv[e]) << 32) | (unsigned)i;
    unsigned long long pi = ((unsigned long long)__float_as_uint(iuv[e]) << 32) | (unsigned)u;
    int su = atomicAdd(&wpu[u], 1);
    __builtin_nontemporal_store(pu, &cv_u[su]);
    int si = atomicAdd(&wpi[i], 1);
    __builtin_nontemporal_store(pi, &cv_i[si]);
}

// ---------------- gather SpMM (both sides fused; one wave per row) ----------------

template <int STAGE>
__global__ __launch_bounds__(256) void gather_stage(
    const int* __restrict__ rp_u, const int2* __restrict__ cv_u,
    const int* __restrict__ rp_i, const int2* __restrict__ cv_i,
    const float* __restrict__ emb_u, const float* __restrict__ emb_i,
    float* __restrict__ out_u, float* __restrict__ out_i,
    int U, int I)
{
    int wid = (blockIdx.x * blockDim.x + threadIdx.x) >> 6;
    int f   = threadIdx.x & 63;
    if (wid >= U + I) return;

    const int*  rp;  const int2* cv;
    const float* src; int sstride;
    const float* resid; int rstride;
    float* outp; const float* emb;
    int row;
    if (wid < U) {
        row = wid; rp = rp_u; cv = cv_u; outp = out_u; emb = emb_u;
        if (STAGE == 1) { src = emb_i;      sstride = 64;  resid = emb_u;      rstride = 64;  }
        else            { src = out_i + 64; sstride = 192; resid = out_u + 64; rstride = 192; }
    } else {
        row = wid - U; rp = rp_i; cv = cv_i; outp = out_i; emb = emb_i;
        if (STAGE == 1) { src = emb_u;      sstride = 64;  resid = emb_i;      rstride = 64;  }
        else            { src = out_u + 64; sstride = 192; resid = out_i + 64; rstride = 192; }
    }

    int beg = rp[row], end = rp[row + 1];
    float a0 = 0.f, a1 = 0.f, a2 = 0.f, a3 = 0.f;
    int e = beg;
    for (; e + 3 < end; e += 4) {
        int2 c0 = cv[e], c1 = cv[e + 1], c2 = cv[e + 2], c3 = cv[e + 3];
        a0 += __int_as_float(c0.y) * src[c0.x * sstride + f];
        a1 += __int_as_float(c1.y) * src[c1.x * sstride + f];
        a2 += __int_as_float(c2.y) * src[c2.x * sstride + f];
        a3 += __int_as_float(c3.y) * src[c3.x * sstride + f];
    }
    for (; e < end; ++e) {
        int2 c = cv[e];
        a0 += __int_as_float(c.y) * src[c.x * sstride + f];
    }
    float acc = (a0 + a1) + (a2 + a3);
    acc += resid[row * rstride + f];
    int dst_col = (STAGE == 1) ? 64 : 128;
    outp[row * 192 + dst_col + f] = acc;
    if (STAGE == 1) outp[row * 192 + f] = emb[row * 64 + f];
}

// ---------------- fallback (round-1 atomic path) ----------------

__global__ void init_dup_kernel(const float4* __restrict__ src,
                                float4* __restrict__ dst, int nrows)
{
    int gid = blockIdx.x * blockDim.x + threadIdx.x;
    if (gid >= nrows * 16) return;
    int row = gid >> 4, c = gid & 15;
    float4 v = src[gid];
    dst[row * 48 + c]      = v;
    dst[row * 48 + 16 + c] = v;
}

__global__ void copy_col_kernel(float4* __restrict__ buf, int nrows)
{
    int gid = blockIdx.x * blockDim.x + threadIdx.x;
    if (gid >= nrows * 16) return;
    int row = gid >> 4, c = gid & 15;
    buf[row * 48 + 32 + c] = buf[row * 48 + 16 + c];
}

__global__ void spmm_atomic(const int* __restrict__ edge_user,
                            const int* __restrict__ edge_item,
                            const float* __restrict__ ui_vals,
                            const float* __restrict__ iu_vals,
                            const float* __restrict__ src_u, int su,
                            const float* __restrict__ src_i, int si,
                            float* __restrict__ out_u, float* __restrict__ out_i,
                            int dst_col, int E)
{
    int gid = blockIdx.x * blockDim.x + threadIdx.x;
    if (gid >= E * 64) return;
    int e = gid >> 6, f = gid & 63;
    int u = edge_user[e], i = edge_item[e];
    unsafeAtomicAdd(&out_u[u * 192 + dst_col + f], ui_vals[e] * src_i[i * si + f]);
    unsafeAtomicAdd(&out_i[i * 192 + dst_col + f], iu_vals[e] * src_u[u * su + f]);
}

extern "C" void kernel_launch(void* const* d_in, const int* in_sizes, int n_in,
                              void* d_out, int out_size, void* d_ws, size_t ws_size,
                              hipStream_t stream)
{
    const float* emb_u   = (const float*)d_in[0];
    const float* emb_i   = (const float*)d_in[1];
    const float* ui_vals = (const float*)d_in[2];
    const float* iu_vals = (const float*)d_in[3];
    const int*   e_user  = (const int*)d_in[4];
    const int*   e_item  = (const int*)d_in[5];

    const int F = 64;
    const int U = in_sizes[0] / F;
    const int I = in_sizes[1] / F;
    const int E = in_sizes[4];

    float* out_u = (float*)d_out;            // [U][192]
    float* out_i = out_u + (size_t)U * 192;  // [I][192]

    const int BLK = 256;

    // workspace layout (ints): wp_u[U] wp_i[I] rp_u[U+1] rp_i[I+1] bsum[256]
    //                          bscan[256] [pad to even] cv_u[2E] cv_i[2E]
    size_t hdr   = (size_t)U + I + (U + 1) + (I + 1) + 512;
    size_t cvoff = (hdr + 1) & ~(size_t)1;      // 8B-align
    size_t need  = (cvoff + 4 * (size_t)E) * 4;

    if (ws_size >= need) {
        int* wp_u  = (int*)d_ws;
        int* wp_i  = wp_u + U;
        int* rp_u  = wp_i + I;               // U+1
        int* rp_i  = rp_u + (U + 1);         // I+1
        int* bsum  = rp_i + (I + 1);         // 256
        int* bscan = bsum + 256;             // 256
        unsigned long long* cv_u = (unsigned long long*)((int*)d_ws + cvoff);
        unsigned long long* cv_i = cv_u + E;

        // --- build CSR ---
        hipMemsetAsync(wp_u, 0, (size_t)(U + I) * 4, stream);
        count_kernel<<<(E + BLK - 1) / BLK, BLK, 0, stream>>>(e_user, e_item, wp_u, wp_i, E);

        int nb_u = (U + 1023) / 1024, nb_i = (I + 1023) / 1024;
        scan_block_kernel<<<nb_u, 1024, 0, stream>>>(wp_u, U, rp_u, bsum);
        scan_block_kernel<<<1, 1024, 0, stream>>>(bsum, nb_u, bscan, nullptr);
        scan_fixup_kernel<<<(U + 1 + BLK - 1) / BLK, BLK, 0, stream>>>(rp_u, wp_u, bscan, U, E);
        scan_block_kernel<<<nb_i, 1024, 0, stream>>>(wp_i, I, rp_i, bsum);
        scan_block_kernel<<<1, 1024, 0, stream>>>(bsum, nb_i, bscan, nullptr);
        scan_fixup_kernel<<<(I + 1 + BLK - 1) / BLK, BLK, 0, stream>>>(rp_i, wp_i, bscan, I, E);

        scatter_kernel<<<(E + BLK - 1) / BLK, BLK, 0, stream>>>(
            e_user, e_item, ui_vals, iu_vals, wp_u, wp_i, cv_u, cv_i, E);

        // --- stage 1: gcn1 = spmm(emb) + emb (also copies emb to col 0) ---
        int grid_g = ((U + I) * 64 + BLK - 1) / BLK;
        gather_stage<1><<<grid_g, BLK, 0, stream>>>(
            rp_u, (const int2*)cv_u, rp_i, (const int2*)cv_i,
            emb_u, emb_i, out_u, out_i, U, I);

        // --- stage 2: gcn2 = spmm(gcn1_other) + gcn1 ---
        gather_stage<2><<<grid_g, BLK, 0, stream>>>(
            rp_u, (const int2*)cv_u, rp_i, (const int2*)cv_i,
            emb_u, emb_i, out_u, out_i, U, I);
    } else {
        // fallback: atomic scatter path
        int grid_u = (U * 16 + BLK - 1) / BLK;
        int grid_i = (I * 16 + BLK - 1) / BLK;
        long long t = (long long)E * 64;
        int grid_e = (int)((t + BLK - 1) / BLK);
        init_dup_kernel<<<grid_u, BLK, 0, stream>>>((const float4*)emb_u, (float4*)out_u, U);
        init_dup_kernel<<<grid_i, BLK, 0, stream>>>((const float4*)emb_i, (float4*)out_i, I);
        spmm_atomic<<<grid_e, BLK, 0, stream>>>(e_user, e_item, ui_vals, iu_vals,
                                                emb_u, 64, emb_i, 64, out_u, out_i, 64, E);
        copy_col_kernel<<<grid_u, BLK, 0, stream>>>((float4*)out_u, U);
        copy_col_kernel<<<grid_i, BLK, 0, stream>>>((float4*)out_i, I);
        spmm_atomic<<<grid_e, BLK, 0, stream>>>(e_user, e_item, ui_vals, iu_vals,
                                                out_u + 64, 192, out_i + 64, 192,
                                                out_u, out_i, 128, E);
    }
}

// Round 4
// 632.085 us; speedup vs baseline: 1.1443x; 1.1443x over previous
//
#include <hip/hip_runtime.h>

// d_out layout: gcn_users [U][192] then gcn_items [I][192]
//   cols 0:64 = emb, 64:128 = gcn1, 128:192 = gcn2
//
// CSR built per launch via two-pass binned scatter (radix-by-bucket), then
// gather SpMM (one wave per output row), no output atomics.

typedef unsigned long long ull;

// ---------------- CSR build ----------------

__global__ void count_kernel(const int* __restrict__ eu, const int* __restrict__ ei,
                             int* __restrict__ du, int* __restrict__ di, int E)
{
    int e = blockIdx.x * blockDim.x + threadIdx.x;
    if (e >= E) return;
    atomicAdd(&du[eu[e]], 1);
    atomicAdd(&di[ei[e]], 1);
}

// Exclusive scan within each 1024-block; block totals to bsums (if non-null).
__global__ void scan_block_kernel(const int* __restrict__ in, int n,
                                  int* __restrict__ out, int* __restrict__ bsums)
{
    __shared__ int tmp[1024];
    int idx = blockIdx.x * 1024 + threadIdx.x;
    int x = (idx < n) ? in[idx] : 0;
    tmp[threadIdx.x] = x;
    __syncthreads();
    #pragma unroll
    for (int off = 1; off < 1024; off <<= 1) {
        int t = (threadIdx.x >= off) ? tmp[threadIdx.x - off] : 0;
        __syncthreads();
        tmp[threadIdx.x] += t;
        __syncthreads();
    }
    if (idx < n) out[idx] = tmp[threadIdx.x] - x;
    if (threadIdx.x == 1023 && bsums) bsums[blockIdx.x] = tmp[1023];
}

// rp[idx] += block offset; optionally mirror into wp (fallback path).
__global__ void scan_fixup_kernel(int* __restrict__ rp, int* __restrict__ wp,
                                  const int* __restrict__ bscan, int n, int total)
{
    int idx = blockIdx.x * blockDim.x + threadIdx.x;
    if (idx < n) {
        int v = rp[idx] + bscan[idx >> 10];
        rp[idx] = v;
        if (wp) wp[idx] = v;
    } else if (idx == n) {
        rp[n] = total;
    }
}

// bwp[b*16] = rp[min(b*ROWS, n)]  (padded: one counter per 64B line)
__global__ void bwp_init_kernel(const int* __restrict__ rp_u, const int* __restrict__ rp_i,
                                int* __restrict__ bwp_u, int* __restrict__ bwp_i,
                                int nb_u, int nb_i, int U, int I)
{
    int idx = blockIdx.x * blockDim.x + threadIdx.x;
    if (idx < nb_u) bwp_u[idx * 16] = rp_u[min(idx << 7, U)];
    if (idx < nb_i) bwp_i[idx * 16] = rp_i[min(idx << 6, I)];
}

// Pass 1: bin edges by row-bucket. Bucket tails are append-contiguous.
__global__ void bin_kernel(const int* __restrict__ eu, const int* __restrict__ ei,
                           const float* __restrict__ uiv, const float* __restrict__ iuv,
                           int* __restrict__ bwp_u, int* __restrict__ bwp_i,
                           ull* __restrict__ scv_u, unsigned short* __restrict__ srow_u,
                           ull* __restrict__ scv_i, unsigned short* __restrict__ srow_i,
                           int E)
{
    int e = blockIdx.x * blockDim.x + threadIdx.x;
    if (e >= E) return;
    int u = eu[e], it = ei[e];
    ull pu = ((ull)__float_as_uint(uiv[e]) << 32) | (unsigned)it;
    ull pi = ((ull)__float_as_uint(iuv[e]) << 32) | (unsigned)u;
    int posu = atomicAdd(&bwp_u[(u >> 7) * 16], 1);
    scv_u[posu]  = pu;
    srow_u[posu] = (unsigned short)(u & 127);
    int posi = atomicAdd(&bwp_i[(it >> 6) * 16], 1);
    scv_i[posi]  = pi;
    srow_i[posi] = (unsigned short)(it & 63);
}

// Pass 2: one WG per bucket; per-row write pointers in LDS; output writes are
// random only within the bucket's ~16KB cv range (single-XCD L2 resident).
__global__ __launch_bounds__(256) void place_kernel(
    const int* __restrict__ rp, const ull* __restrict__ scv,
    const unsigned short* __restrict__ srow, ull* __restrict__ cv,
    int rows_log2, int nrows)
{
    __shared__ int wp[256];
    int b    = blockIdx.x;
    int u0   = b << rows_log2;
    int u1   = min(u0 + (1 << rows_log2), nrows);
    int nr   = u1 - u0;
    if (nr <= 0) return;
    int base = rp[u0];
    int cnt  = rp[u1] - base;
    if ((int)threadIdx.x < nr) wp[threadIdx.x] = rp[u0 + threadIdx.x] - base;
    __syncthreads();
    for (int k = threadIdx.x; k < cnt; k += blockDim.x) {
        int r   = srow[base + k];
        int dst = atomicAdd(&wp[r], 1);
        cv[base + dst] = scv[base + k];
    }
}

// Fallback (round-3): direct random scatter.
__global__ void scatter_kernel(const int* __restrict__ eu, const int* __restrict__ ei,
                               const float* __restrict__ uiv, const float* __restrict__ iuv,
                               int* __restrict__ wpu, int* __restrict__ wpi,
                               ull* __restrict__ cv_u, ull* __restrict__ cv_i, int E)
{
    int e = blockIdx.x * blockDim.x + threadIdx.x;
    if (e >= E) return;
    int u = eu[e], i = ei[e];
    ull pu = ((ull)__float_as_uint(uiv[e]) << 32) | (unsigned)i;
    ull pi = ((ull)__float_as_uint(iuv[e]) << 32) | (unsigned)u;
    int su = atomicAdd(&wpu[u], 1);
    cv_u[su] = pu;
    int si = atomicAdd(&wpi[i], 1);
    cv_i[si] = pi;
}

// ---------------- gather SpMM (both sides fused; one wave per row) ----------------

template <int STAGE>
__global__ __launch_bounds__(256) void gather_stage(
    const int* __restrict__ rp_u, const int2* __restrict__ cv_u,
    const int* __restrict__ rp_i, const int2* __restrict__ cv_i,
    const float* __restrict__ emb_u, const float* __restrict__ emb_i,
    float* __restrict__ out_u, float* __restrict__ out_i,
    int U, int I)
{
    int wid = (blockIdx.x * blockDim.x + threadIdx.x) >> 6;
    int f   = threadIdx.x & 63;
    if (wid >= U + I) return;

    const int*  rp;  const int2* cv;
    const float* src; int sstride;
    const float* resid; int rstride;
    float* outp; const float* emb;
    int row;
    if (wid < U) {
        row = wid; rp = rp_u; cv = cv_u; outp = out_u; emb = emb_u;
        if (STAGE == 1) { src = emb_i;      sstride = 64;  resid = emb_u;      rstride = 64;  }
        else            { src = out_i + 64; sstride = 192; resid = out_u + 64; rstride = 192; }
    } else {
        row = wid - U; rp = rp_i; cv = cv_i; outp = out_i; emb = emb_i;
        if (STAGE == 1) { src = emb_u;      sstride = 64;  resid = emb_i;      rstride = 64;  }
        else            { src = out_u + 64; sstride = 192; resid = out_i + 64; rstride = 192; }
    }

    int beg = rp[row], end = rp[row + 1];
    float a0 = 0.f, a1 = 0.f, a2 = 0.f, a3 = 0.f;
    int e = beg;
    for (; e + 3 < end; e += 4) {
        int2 c0 = cv[e], c1 = cv[e + 1], c2 = cv[e + 2], c3 = cv[e + 3];
        a0 += __int_as_float(c0.y) * src[c0.x * sstride + f];
        a1 += __int_as_float(c1.y) * src[c1.x * sstride + f];
        a2 += __int_as_float(c2.y) * src[c2.x * sstride + f];
        a3 += __int_as_float(c3.y) * src[c3.x * sstride + f];
    }
    for (; e < end; ++e) {
        int2 c = cv[e];
        a0 += __int_as_float(c.y) * src[c.x * sstride + f];
    }
    float acc = (a0 + a1) + (a2 + a3);
    acc += resid[row * rstride + f];
    int dst_col = (STAGE == 1) ? 64 : 128;
    outp[row * 192 + dst_col + f] = acc;
    if (STAGE == 1) outp[row * 192 + f] = emb[row * 64 + f];
}

extern "C" void kernel_launch(void* const* d_in, const int* in_sizes, int n_in,
                              void* d_out, int out_size, void* d_ws, size_t ws_size,
                              hipStream_t stream)
{
    const float* emb_u   = (const float*)d_in[0];
    const float* emb_i   = (const float*)d_in[1];
    const float* ui_vals = (const float*)d_in[2];
    const float* iu_vals = (const float*)d_in[3];
    const int*   e_user  = (const int*)d_in[4];
    const int*   e_item  = (const int*)d_in[5];

    const int F = 64;
    const int U = in_sizes[0] / F;
    const int I = in_sizes[1] / F;
    const int E = in_sizes[4];

    float* out_u = (float*)d_out;            // [U][192]
    float* out_i = out_u + (size_t)U * 192;  // [I][192]

    const int BLK = 256;
    const int LOG_RU = 7, LOG_RI = 6;        // 128 users / 64 items per bucket
    int nb_u = (U + (1 << LOG_RU) - 1) >> LOG_RU;
    int nb_i = (I + (1 << LOG_RI) - 1) >> LOG_RI;

    // ---- workspace bump allocator ----
    char* base = (char*)d_ws;
    size_t off = 0;
    auto alloc = [&](size_t bytes, size_t align) -> char* {
        off = (off + align - 1) & ~(align - 1);
        char* p = base + off;
        off += bytes;
        return p;
    };
    int* deg_u  = (int*)alloc((size_t)U * 4, 4);         // also fallback wp
    int* deg_i  = (int*)alloc((size_t)I * 4, 4);
    int* rp_u   = (int*)alloc((size_t)(U + 1) * 4, 4);
    int* rp_i   = (int*)alloc((size_t)(I + 1) * 4, 4);
    int* bsum   = (int*)alloc(1024 * 4, 4);
    int* bscan  = (int*)alloc(1024 * 4, 4);
    int* bwp_u  = (int*)alloc((size_t)nb_u * 64, 64);
    int* bwp_i  = (int*)alloc((size_t)nb_i * 64, 64);
    ull* cv_u   = (ull*)alloc((size_t)E * 8, 8);
    ull* cv_i   = (ull*)alloc((size_t)E * 8, 8);
    size_t need_small = off;                              // through cv arrays
    ull* scv_u  = (ull*)alloc((size_t)E * 8, 8);
    ull* scv_i  = (ull*)alloc((size_t)E * 8, 8);
    unsigned short* srow_u = (unsigned short*)alloc((size_t)E * 2, 2);
    unsigned short* srow_i = (unsigned short*)alloc((size_t)E * 2, 2);
    size_t need_full = off;

    bool full = ws_size >= need_full;
    if (ws_size < need_small) return;  // cannot run (not expected on this harness)

    // ---- degree count + row pointers ----
    hipMemsetAsync(deg_u, 0, ((size_t)U + I) * 4, stream);
    count_kernel<<<(E + BLK - 1) / BLK, BLK, 0, stream>>>(e_user, e_item, deg_u, deg_i, E);

    int sb_u = (U + 1023) / 1024, sb_i = (I + 1023) / 1024;
    scan_block_kernel<<<sb_u, 1024, 0, stream>>>(deg_u, U, rp_u, bsum);
    scan_block_kernel<<<1, 1024, 0, stream>>>(bsum, sb_u, bscan, nullptr);
    scan_fixup_kernel<<<(U + 1 + BLK - 1) / BLK, BLK, 0, stream>>>(
        rp_u, full ? nullptr : deg_u, bscan, U, E);
    scan_block_kernel<<<sb_i, 1024, 0, stream>>>(deg_i, I, rp_i, bsum);
    scan_block_kernel<<<1, 1024, 0, stream>>>(bsum, sb_i, bscan, nullptr);
    scan_fixup_kernel<<<(I + 1 + BLK - 1) / BLK, BLK, 0, stream>>>(
        rp_i, full ? nullptr : deg_i, bscan, I, E);

    if (full) {
        // ---- two-pass binned scatter ----
        int nbmax = max(nb_u, nb_i);
        bwp_init_kernel<<<(nbmax + BLK - 1) / BLK, BLK, 0, stream>>>(
            rp_u, rp_i, bwp_u, bwp_i, nb_u, nb_i, U, I);
        bin_kernel<<<(E + BLK - 1) / BLK, BLK, 0, stream>>>(
            e_user, e_item, ui_vals, iu_vals, bwp_u, bwp_i,
            scv_u, srow_u, scv_i, srow_i, E);
        place_kernel<<<nb_u, BLK, 0, stream>>>(rp_u, scv_u, srow_u, cv_u, LOG_RU, U);
        place_kernel<<<nb_i, BLK, 0, stream>>>(rp_i, scv_i, srow_i, cv_i, LOG_RI, I);
    } else {
        // ---- fallback: direct random scatter (round-3 path) ----
        scatter_kernel<<<(E + BLK - 1) / BLK, BLK, 0, stream>>>(
            e_user, e_item, ui_vals, iu_vals, deg_u, deg_i, cv_u, cv_i, E);
    }

    // ---- stage 1: gcn1 = spmm(emb) + emb (also copies emb to col 0) ----
    int grid_g = ((U + I) * 64 + BLK - 1) / BLK;
    gather_stage<1><<<grid_g, BLK, 0, stream>>>(
        rp_u, (const int2*)cv_u, rp_i, (const int2*)cv_i,
        emb_u, emb_i, out_u, out_i, U, I);

    // ---- stage 2: gcn2 = spmm(gcn1_other) + gcn1 ----
    gather_stage<2><<<grid_g, BLK, 0, stream>>>(
        rp_u, (const int2*)cv_u, rp_i, (const int2*)cv_i,
        emb_u, emb_i, out_u, out_i, U, I);
}

// Round 5
// 519.111 us; speedup vs baseline: 1.3933x; 1.2176x over previous
//
#include <hip/hip_runtime.h>

// d_out layout: gcn_users [U][192] then gcn_items [I][192]
//   cols 0:64 = emb, 64:128 = gcn1, 128:192 = gcn2
//
// CSR built per launch: per-row degrees+scan, then TILED TWO-PHASE binning
// (count in LDS -> one global reservation per (tile,bucket) -> contiguous run
// writes), then per-bucket place (LDS write pointers), then gather SpMM.
// Staging entry packs (col:24 | row-in-bucket:8 | val:32) in one 8B word.

typedef unsigned long long ull;

// ---------------- CSR build ----------------

__global__ void count_kernel(const int* __restrict__ eu, const int* __restrict__ ei,
                             int* __restrict__ du, int* __restrict__ di, int E)
{
    int e = blockIdx.x * blockDim.x + threadIdx.x;
    if (e >= E) return;
    atomicAdd(&du[eu[e]], 1);
    atomicAdd(&di[ei[e]], 1);
}

// Exclusive scan within each 1024-block; block totals to bsums (if non-null).
__global__ void scan_block_kernel(const int* __restrict__ in, int n,
                                  int* __restrict__ out, int* __restrict__ bsums)
{
    __shared__ int tmp[1024];
    int idx = blockIdx.x * 1024 + threadIdx.x;
    int x = (idx < n) ? in[idx] : 0;
    tmp[threadIdx.x] = x;
    __syncthreads();
    #pragma unroll
    for (int off = 1; off < 1024; off <<= 1) {
        int t = (threadIdx.x >= off) ? tmp[threadIdx.x - off] : 0;
        __syncthreads();
        tmp[threadIdx.x] += t;
        __syncthreads();
    }
    if (idx < n) out[idx] = tmp[threadIdx.x] - x;
    if (threadIdx.x == 1023 && bsums) bsums[blockIdx.x] = tmp[1023];
}

// rp[idx] += block offset; optionally mirror into wp (fallback path).
__global__ void scan_fixup_kernel(int* __restrict__ rp, int* __restrict__ wp,
                                  const int* __restrict__ bscan, int n, int total)
{
    int idx = blockIdx.x * blockDim.x + threadIdx.x;
    if (idx < n) {
        int v = rp[idx] + bscan[idx >> 10];
        rp[idx] = v;
        if (wp) wp[idx] = v;
    } else if (idx == n) {
        rp[n] = total;
    }
}

// gwp[b] = rp[min(b*ROWS, n)]  (bucket write pointers, unpadded)
__global__ void bwp_init_kernel(const int* __restrict__ rp_u, const int* __restrict__ rp_i,
                                int* __restrict__ gwp_u, int* __restrict__ gwp_i,
                                int nb_u, int nb_i, int U, int I)
{
    int idx = blockIdx.x * blockDim.x + threadIdx.x;
    if (idx < nb_u) gwp_u[idx] = rp_u[min(idx << 7, U)];
    if (idx < nb_i) gwp_i[idx] = rp_i[min(idx << 6, I)];
}

// Tiled two-phase binning: per tile of TILE edges, (A) count buckets in LDS,
// (B) one global atomicAdd per non-empty bucket to reserve a contiguous run,
// (C) write entries into the run. Runs are written by one WG at one time ->
// line-granular writebacks happen once.
#define TILE 8192
__global__ __launch_bounds__(256) void bin2_kernel(
    const int* __restrict__ eu, const int* __restrict__ ei,
    const float* __restrict__ uiv, const float* __restrict__ iuv,
    int* __restrict__ gwp_u, int* __restrict__ gwp_i,
    ull* __restrict__ scv_u, ull* __restrict__ scv_i,
    int E, int nb_u, int nb_i)
{
    __shared__ int cnt[1024];
    __shared__ int base[1024];
    int tile0 = blockIdx.x * TILE;
    int n = min(TILE, E - tile0);

    // ---------- side U (bucket = u>>7, row = u&127, col = item) ----------
    for (int b = threadIdx.x; b < nb_u; b += 256) cnt[b] = 0;
    __syncthreads();
    for (int k = threadIdx.x; k < n; k += 256)
        atomicAdd(&cnt[eu[tile0 + k] >> 7], 1);
    __syncthreads();
    for (int b = threadIdx.x; b < nb_u; b += 256) {
        int c = cnt[b];
        base[b] = c ? atomicAdd(&gwp_u[b], c) : 0;
        cnt[b] = 0;
    }
    __syncthreads();
    for (int k = threadIdx.x; k < n; k += 256) {
        int u  = eu[tile0 + k];
        int it = ei[tile0 + k];
        float v = uiv[tile0 + k];
        int b = u >> 7;
        int pos = base[b] + atomicAdd(&cnt[b], 1);
        scv_u[pos] = ((ull)__float_as_uint(v) << 32) |
                     ((ull)(u & 127) << 24) | (unsigned)it;
    }
    __syncthreads();

    // ---------- side I (bucket = i>>6, row = i&63, col = user) ----------
    for (int b = threadIdx.x; b < nb_i; b += 256) cnt[b] = 0;
    __syncthreads();
    for (int k = threadIdx.x; k < n; k += 256)
        atomicAdd(&cnt[ei[tile0 + k] >> 6], 1);
    __syncthreads();
    for (int b = threadIdx.x; b < nb_i; b += 256) {
        int c = cnt[b];
        base[b] = c ? atomicAdd(&gwp_i[b], c) : 0;
        cnt[b] = 0;
    }
    __syncthreads();
    for (int k = threadIdx.x; k < n; k += 256) {
        int it = ei[tile0 + k];
        int u  = eu[tile0 + k];
        float v = iuv[tile0 + k];
        int b = it >> 6;
        int pos = base[b] + atomicAdd(&cnt[b], 1);
        scv_i[pos] = ((ull)__float_as_uint(v) << 32) |
                     ((ull)(it & 63) << 24) | (unsigned)u;
    }
}

// Per-bucket place: LDS per-row write pointers; writes random only within the
// bucket's ~16KB cv range (single-XCD L2 resident).
__global__ __launch_bounds__(256) void place_kernel(
    const int* __restrict__ rp, const ull* __restrict__ scv,
    int2* __restrict__ cv, int rows_log2, int nrows)
{
    __shared__ int wp[256];
    int b  = blockIdx.x;
    int u0 = b << rows_log2;
    int u1 = min(u0 + (1 << rows_log2), nrows);
    int nr = u1 - u0;
    if (nr <= 0) return;
    int bbase = rp[u0];
    int cnt   = rp[u1] - bbase;
    if ((int)threadIdx.x < nr) wp[threadIdx.x] = rp[u0 + threadIdx.x] - bbase;
    __syncthreads();
    for (int k = threadIdx.x; k < cnt; k += blockDim.x) {
        ull w = scv[bbase + k];
        int r = (int)((w >> 24) & 255);
        int dst = atomicAdd(&wp[r], 1);
        cv[bbase + dst] = make_int2((int)(w & 0xFFFFFF), (int)(w >> 32));
    }
}

// Fallback: direct random scatter (round-3 path).
__global__ void scatter_kernel(const int* __restrict__ eu, const int* __restrict__ ei,
                               const float* __restrict__ uiv, const float* __restrict__ iuv,
                               int* __restrict__ wpu, int* __restrict__ wpi,
                               ull* __restrict__ cv_u, ull* __restrict__ cv_i, int E)
{
    int e = blockIdx.x * blockDim.x + threadIdx.x;
    if (e >= E) return;
    int u = eu[e], i = ei[e];
    ull pu = ((ull)__float_as_uint(uiv[e]) << 32) | (unsigned)i;
    ull pi = ((ull)__float_as_uint(iuv[e]) << 32) | (unsigned)u;
    int su = atomicAdd(&wpu[u], 1);
    cv_u[su] = pu;
    int si = atomicAdd(&wpi[i], 1);
    cv_i[si] = pi;
}

// ---------------- gather SpMM (both sides fused; one wave per row) ----------------

template <int STAGE>
__global__ __launch_bounds__(256) void gather_stage(
    const int* __restrict__ rp_u, const int2* __restrict__ cv_u,
    const int* __restrict__ rp_i, const int2* __restrict__ cv_i,
    const float* __restrict__ emb_u, const float* __restrict__ emb_i,
    float* __restrict__ out_u, float* __restrict__ out_i,
    int U, int I)
{
    int wid = (blockIdx.x * blockDim.x + threadIdx.x) >> 6;
    int f   = threadIdx.x & 63;
    if (wid >= U + I) return;

    const int*  rp;  const int2* cv;
    const float* src; int sstride;
    const float* resid; int rstride;
    float* outp; const float* emb;
    int row;
    if (wid < U) {
        row = wid; rp = rp_u; cv = cv_u; outp = out_u; emb = emb_u;
        if (STAGE == 1) { src = emb_i;      sstride = 64;  resid = emb_u;      rstride = 64;  }
        else            { src = out_i + 64; sstride = 192; resid = out_u + 64; rstride = 192; }
    } else {
        row = wid - U; rp = rp_i; cv = cv_i; outp = out_i; emb = emb_i;
        if (STAGE == 1) { src = emb_u;      sstride = 64;  resid = emb_i;      rstride = 64;  }
        else            { src = out_u + 64; sstride = 192; resid = out_i + 64; rstride = 192; }
    }

    int beg = rp[row], end = rp[row + 1];
    float a0 = 0.f, a1 = 0.f, a2 = 0.f, a3 = 0.f;
    int e = beg;
    for (; e + 3 < end; e += 4) {
        int2 c0 = cv[e], c1 = cv[e + 1], c2 = cv[e + 2], c3 = cv[e + 3];
        a0 += __int_as_float(c0.y) * src[c0.x * sstride + f];
        a1 += __int_as_float(c1.y) * src[c1.x * sstride + f];
        a2 += __int_as_float(c2.y) * src[c2.x * sstride + f];
        a3 += __int_as_float(c3.y) * src[c3.x * sstride + f];
    }
    for (; e < end; ++e) {
        int2 c = cv[e];
        a0 += __int_as_float(c.y) * src[c.x * sstride + f];
    }
    float acc = (a0 + a1) + (a2 + a3);
    acc += resid[row * rstride + f];
    int dst_col = (STAGE == 1) ? 64 : 128;
    outp[row * 192 + dst_col + f] = acc;
    if (STAGE == 1) outp[row * 192 + f] = emb[row * 64 + f];
}

extern "C" void kernel_launch(void* const* d_in, const int* in_sizes, int n_in,
                              void* d_out, int out_size, void* d_ws, size_t ws_size,
                              hipStream_t stream)
{
    const float* emb_u   = (const float*)d_in[0];
    const float* emb_i   = (const float*)d_in[1];
    const float* ui_vals = (const float*)d_in[2];
    const float* iu_vals = (const float*)d_in[3];
    const int*   e_user  = (const int*)d_in[4];
    const int*   e_item  = (const int*)d_in[5];

    const int F = 64;
    const int U = in_sizes[0] / F;
    const int I = in_sizes[1] / F;
    const int E = in_sizes[4];

    float* out_u = (float*)d_out;            // [U][192]
    float* out_i = out_u + (size_t)U * 192;  // [I][192]

    const int BLK = 256;
    const int LOG_RU = 7, LOG_RI = 6;        // 128 users / 64 items per bucket
    int nb_u = (U + (1 << LOG_RU) - 1) >> LOG_RU;
    int nb_i = (I + (1 << LOG_RI) - 1) >> LOG_RI;

    // ---- workspace bump allocator ----
    char* base = (char*)d_ws;
    size_t off = 0;
    auto alloc = [&](size_t bytes, size_t align) -> char* {
        off = (off + align - 1) & ~(align - 1);
        char* p = base + off;
        off += bytes;
        return p;
    };
    int* deg_u  = (int*)alloc((size_t)U * 4, 4);         // also fallback wp
    int* deg_i  = (int*)alloc((size_t)I * 4, 4);
    int* rp_u   = (int*)alloc((size_t)(U + 1) * 4, 4);
    int* rp_i   = (int*)alloc((size_t)(I + 1) * 4, 4);
    int* bsum   = (int*)alloc(1024 * 4, 4);
    int* bscan  = (int*)alloc(1024 * 4, 4);
    int* gwp_u  = (int*)alloc((size_t)nb_u * 4, 64);
    int* gwp_i  = (int*)alloc((size_t)nb_i * 4, 64);
    ull* cv_u   = (ull*)alloc((size_t)E * 8, 8);
    ull* cv_i   = (ull*)alloc((size_t)E * 8, 8);
    size_t need_small = off;                              // through cv arrays
    ull* scv_u  = (ull*)alloc((size_t)E * 8, 8);
    ull* scv_i  = (ull*)alloc((size_t)E * 8, 8);
    size_t need_full = off;

    bool full = ws_size >= need_full && nb_u <= 1024 && nb_i <= 1024;
    if (ws_size < need_small) return;  // cannot run (not expected on this harness)

    // ---- degree count + row pointers ----
    hipMemsetAsync(deg_u, 0, ((size_t)U + I) * 4, stream);
    count_kernel<<<(E + BLK - 1) / BLK, BLK, 0, stream>>>(e_user, e_item, deg_u, deg_i, E);

    int sb_u = (U + 1023) / 1024, sb_i = (I + 1023) / 1024;
    scan_block_kernel<<<sb_u, 1024, 0, stream>>>(deg_u, U, rp_u, bsum);
    scan_block_kernel<<<1, 1024, 0, stream>>>(bsum, sb_u, bscan, nullptr);
    scan_fixup_kernel<<<(U + 1 + BLK - 1) / BLK, BLK, 0, stream>>>(
        rp_u, full ? nullptr : deg_u, bscan, U, E);
    scan_block_kernel<<<sb_i, 1024, 0, stream>>>(deg_i, I, rp_i, bsum);
    scan_block_kernel<<<1, 1024, 0, stream>>>(bsum, sb_i, bscan, nullptr);
    scan_fixup_kernel<<<(I + 1 + BLK - 1) / BLK, BLK, 0, stream>>>(
        rp_i, full ? nullptr : deg_i, bscan, I, E);

    if (full) {
        // ---- tiled two-phase binning + per-bucket place ----
        int nbmax = max(nb_u, nb_i);
        bwp_init_kernel<<<(nbmax + BLK - 1) / BLK, BLK, 0, stream>>>(
            rp_u, rp_i, gwp_u, gwp_i, nb_u, nb_i, U, I);
        int ntiles = (E + TILE - 1) / TILE;
        bin2_kernel<<<ntiles, BLK, 0, stream>>>(
            e_user, e_item, ui_vals, iu_vals, gwp_u, gwp_i,
            scv_u, scv_i, E, nb_u, nb_i);
        place_kernel<<<nb_u, BLK, 0, stream>>>(rp_u, scv_u, (int2*)cv_u, LOG_RU, U);
        place_kernel<<<nb_i, BLK, 0, stream>>>(rp_i, scv_i, (int2*)cv_i, LOG_RI, I);
    } else {
        // ---- fallback: direct random scatter ----
        scatter_kernel<<<(E + BLK - 1) / BLK, BLK, 0, stream>>>(
            e_user, e_item, ui_vals, iu_vals, deg_u, deg_i, cv_u, cv_i, E);
    }

    // ---- stage 1: gcn1 = spmm(emb) + emb (also copies emb to col 0) ----
    int grid_g = ((U + I) * 64 + BLK - 1) / BLK;
    gather_stage<1><<<grid_g, BLK, 0, stream>>>(
        rp_u, (const int2*)cv_u, rp_i, (const int2*)cv_i,
        emb_u, emb_i, out_u, out_i, U, I);

    // ---- stage 2: gcn2 = spmm(gcn1_other) + gcn1 ----
    gather_stage<2><<<grid_g, BLK, 0, stream>>>(
        rp_u, (const int2*)cv_u, rp_i, (const int2*)cv_i,
        emb_u, emb_i, out_u, out_i, U, I);
}